// Round 1
// baseline (51.313 us; speedup 1.0000x reference)
//
#include <hip/hip_runtime.h>

// Problem constants (match reference): B=8, N=1024, F=128, H=4, K=32, TAU=1
#define PPB 8  // points per block in phase 1

// ---------------------------------------------------------------------------
// Phase 1: per point bn in [0, 8192):
//   dist[hk] = sum_f |keys[hk][f] - x[bn][f]|        (L1, 128 keys x 128 feat)
//   t[hk]    = 1/(1+dist^2)                           (Student-t, tau=1)
//   snorm    = t / sum_k t  (per head h = hk>>5)
//   sc[k]    = sum_h conv_w[h] * snorm[h*32+k]
//   S[bn][k] = softmax_k(sc)
// Thread layout: 256 threads = (hk in [0,128)) x (half in {0,1});
// each thread holds 64 key features in registers.
// ---------------------------------------------------------------------------
__global__ __launch_bounds__(256) void mempool_phase1(
    const float* __restrict__ x, const float* __restrict__ keys,
    const float* __restrict__ conv_w, float* __restrict__ S_out) {
  const int t = threadIdx.x;
  const int hk = t & 127;
  const int half = t >> 7;

  // Load this thread's 64 key features (16 float4) into registers.
  const float4* kq = reinterpret_cast<const float4*>(keys) + hk * 32 + half * 16;
  float4 key[16];
#pragma unroll
  for (int j = 0; j < 16; ++j) key[j] = kq[j];

  const float cw = conv_w[(t >> 5) & 3];  // = conv_w[h] for t<128

  __shared__ float lds_half[128];
  __shared__ float lds_ws[128];

  const int base = blockIdx.x * PPB;
  for (int p = 0; p < PPB; ++p) {
    const int bn = base + p;
    const float4* xq = reinterpret_cast<const float4*>(x) + bn * 32 + half * 16;
    float a0 = 0.f, a1 = 0.f;
#pragma unroll
    for (int j = 0; j < 16; ++j) {
      float4 xv = xq[j];
      a0 += fabsf(key[j].x - xv.x) + fabsf(key[j].y - xv.y);
      a1 += fabsf(key[j].z - xv.z) + fabsf(key[j].w - xv.w);
    }
    const float acc = a0 + a1;

    if (t >= 128) lds_half[hk] = acc;
    __syncthreads();
    if (t < 128) {
      const float d = acc + lds_half[hk];
      const float tv = 1.0f / (1.0f + d * d);
      // per-head sum over k (32-lane groups: masks 1..16 stay in-group)
      float hs = tv;
#pragma unroll
      for (int m = 1; m < 32; m <<= 1) hs += __shfl_xor(hs, m);
      const float sn = tv / hs;
      lds_ws[hk] = cw * sn;  // conv_w[h] * S[b,h,n,k]
    }
    __syncthreads();
    if (t < 32) {
      // sum over heads, then softmax over k across lanes 0..31
      float sc = lds_ws[t] + lds_ws[32 + t] + lds_ws[64 + t] + lds_ws[96 + t];
      float mx = sc;
#pragma unroll
      for (int m = 1; m < 32; m <<= 1) mx = fmaxf(mx, __shfl_xor(mx, m));
      const float e = expf(sc - mx);
      float se = e;
#pragma unroll
      for (int m = 1; m < 32; m <<= 1) se += __shfl_xor(se, m);
      S_out[bn * 32 + t] = e / se;
    }
    __syncthreads();  // protect lds_half/lds_ws for next point
  }
}

// ---------------------------------------------------------------------------
// Phase 2: per (b,k):
//   pooled[f] = sum_n S[b][n][k] * x[b][n][f]   (n = 1024)
//   out[b][k][fo] = leakyrelu( sum_f pooled[f] * lin_w[fo][f] )
// 256 blocks = (b,k); 256 threads = (fq in [0,32)) x (seg in [0,8)).
// ---------------------------------------------------------------------------
__global__ __launch_bounds__(256) void mempool_phase2(
    const float* __restrict__ x, const float* __restrict__ S,
    const float* __restrict__ lin_w, float* __restrict__ out) {
  const int b = blockIdx.x >> 5;
  const int k = blockIdx.x & 31;
  const int t = threadIdx.x;
  const int fq = t & 31;   // feature quad index
  const int seg = t >> 5;  // n segment (128 each)

  const float4* xq = reinterpret_cast<const float4*>(x) + (size_t)b * 1024 * 32;
  const float* Sb = S + (size_t)b * 1024 * 32 + k;

  float4 acc = {0.f, 0.f, 0.f, 0.f};
  const int n0 = seg * 128;
#pragma unroll 4
  for (int n = n0; n < n0 + 128; ++n) {
    const float sv = Sb[(size_t)n * 32];
    const float4 xv = xq[n * 32 + fq];
    acc.x += sv * xv.x;
    acc.y += sv * xv.y;
    acc.z += sv * xv.z;
    acc.w += sv * xv.w;
  }

  __shared__ float4 red[8][32];
  red[seg][fq] = acc;
  __syncthreads();

  __shared__ float4 pooled4[32];
  if (t < 32) {
    float4 a = red[0][t];
#pragma unroll
    for (int ss = 1; ss < 8; ++ss) {
      const float4 r = red[ss][t];
      a.x += r.x;
      a.y += r.y;
      a.z += r.z;
      a.w += r.w;
    }
    pooled4[t] = a;
  }
  __syncthreads();

  if (t < 128) {
    const float4* wq = reinterpret_cast<const float4*>(lin_w) + t * 32;
    float o = 0.f;
#pragma unroll
    for (int j = 0; j < 32; ++j) {
      const float4 w = wq[j];
      const float4 p = pooled4[j];
      o += w.x * p.x + w.y * p.y + w.z * p.z + w.w * p.w;
    }
    o = (o >= 0.f) ? o : 0.01f * o;
    out[(size_t)(b * 32 + k) * 128 + t] = o;
  }
}

extern "C" void kernel_launch(void* const* d_in, const int* in_sizes, int n_in,
                              void* d_out, int out_size, void* d_ws, size_t ws_size,
                              hipStream_t stream) {
  const float* x = (const float*)d_in[0];       // [8,1024,128]
  const float* keys = (const float*)d_in[1];    // [4,32,128]
  const float* conv_w = (const float*)d_in[2];  // [4]
  const float* lin_w = (const float*)d_in[3];   // [128,128]

  float* out = (float*)d_out;            // [8,32,128] = 32768 floats
  float* S_out = (float*)d_out + 32768;  // [8,1024,32] = 262144 floats

  // Phase 1: 8192 points, PPB per block
  mempool_phase1<<<8192 / PPB, 256, 0, stream>>>(x, keys, conv_w, S_out);
  // Phase 2: one block per (b,k)
  mempool_phase2<<<8 * 32, 256, 0, stream>>>(x, S_out, lin_w, out);
}